// Round 14
// baseline (448.751 us; speedup 1.0000x reference)
//
#include <hip/hip_runtime.h>

typedef unsigned short u16;
typedef unsigned int u32;
typedef __bf16 bf16x8 __attribute__((ext_vector_type(8)));
typedef float f32x4 __attribute__((ext_vector_type(4)));

#define S_    896
#define TR_   1643
#define NTOK_ 3286
#define MP_   3328   // 26*128 padded token rows

// ---------- helpers ----------
__device__ __forceinline__ u16 f2bf(float f) {
  u32 u = __builtin_bit_cast(u32, f);
  u = (u + 0x7FFFu + ((u >> 16) & 1u)) >> 16;   // RNE
  return (u16)u;
}

__device__ __forceinline__ void gload16(const void* g, void* l) {
  __builtin_amdgcn_global_load_lds(
      (const __attribute__((address_space(1))) u32*)g,
      (__attribute__((address_space(3))) u32*)l, 16, 0, 0);
}

// ---------- init: inv perm, xmean zero, pad-row zero (o32/obf/gf) ----------
__global__ void k_init(const int* __restrict__ index, int* __restrict__ inv,
                       float* __restrict__ xmean, float* __restrict__ o32,
                       u16* __restrict__ obf, float* __restrict__ gf) {
  int i = blockIdx.x * 256 + threadIdx.x;
  if (i < TR_) inv[index[i]] = i;
  if (i < 6144) xmean[i] = 0.f;
  if (i < 336) gf[(size_t)NTOK_ * 8 + i] = 0.f;         // pad-row gates
  o32[(size_t)NTOK_ * S_ + i] = 0.f;                    // pad rows (also zbuf init)
  obf[(size_t)NTOK_ * S_ + i] = 0;                      // GEMM1 A pad rows
}

// ---------- xmean ----------
__global__ void k_reduce_x(const float* __restrict__ x, float* __restrict__ xmean) {
  int i = blockIdx.x * 256 + threadIdx.x;
  int b = i / 3072, d = i % 3072;
  int s0 = blockIdx.y * 224;
  const float* p = x + (size_t)b * S_ * 3072 + (size_t)s0 * 3072 + d;
  float s = 0.f;
  for (int t = 0; t < 224; ++t) s += p[(size_t)t * 3072];
  atomicAdd(&xmean[i], s * (1.f / (float)S_));
}

// ---------- small gating ----------
__global__ __launch_bounds__(256)
void k_small_gates(const float* __restrict__ xmean,
                   const float* __restrict__ Wsel, const float* __restrict__ bsel,
                   const float* __restrict__ emb,  const float* __restrict__ Wemb,
                   const float* __restrict__ bemb,
                   float* __restrict__ w2buf, float* __restrict__ zpart,
                   float* __restrict__ outw) {
  __shared__ float red[256];
  __shared__ float gl[16];
  __shared__ float el[8];
  int tid = threadIdx.x;
  for (int o = 0; o < 16; ++o) {
    int b = o >> 3, g = o & 7;
    float s = 0.f;
    for (int d = tid; d < 3072; d += 256) s += xmean[b * 3072 + d] * Wsel[d * 8 + g];
    red[tid] = s; __syncthreads();
    for (int st = 128; st > 0; st >>= 1) { if (tid < st) red[tid] += red[tid + st]; __syncthreads(); }
    if (tid == 0) gl[o] = red[0] + bsel[g];
    __syncthreads();
  }
  for (int g = 0; g < 8; ++g) {
    float s = 0.f;
    for (int d = tid; d < 1536; d += 256) s += emb[d] * Wemb[d * 8 + g];
    red[tid] = s; __syncthreads();
    for (int st = 128; st > 0; st >>= 1) { if (tid < st) red[tid] += red[tid + st]; __syncthreads(); }
    if (tid == 0) el[g] = red[0] + bemb[g];
    __syncthreads();
  }
  if (tid == 0) {
    float zp = 0.f;
    for (int i = 0; i < 4; ++i) {
      float e0 = el[2 * i], e1 = el[2 * i + 1];
      float m = fmaxf(e0, e1);
      float x0 = expf(e0 - m), x1 = expf(e1 - m);
      float den = x0 + x1;
      float se0 = x0 / den, se1 = x1 / den;
      zp += (e0 * e0 + e1 * e1) * 0.5f;
      float tsq = 0.f;
      for (int b = 0; b < 2; ++b) {
        float t0 = gl[b * 8 + 2 * i], t1 = gl[b * 8 + 2 * i + 1];
        tsq += t0 * t0 + t1 * t1;
        float mm = fmaxf(t0, t1);
        float y0 = expf(t0 - mm), y1 = expf(t1 - mm);
        float dd = y0 + y1;
        float w0 = (y0 / dd + se0) * 0.5f, w1 = (y1 / dd + se1) * 0.5f;
        w2buf[b * 8 + 2 * i] = w0; w2buf[b * 8 + 2 * i + 1] = w1;
        outw[b * 8 + 2 * i]  = w0; outw[b * 8 + 2 * i + 1]  = w1;
      }
      zp += tsq * 0.25f;
    }
    *zpart = zp;
  }
}

// ---------- gather (LDS-tiled transpose, both sides coalesced) ----------
__global__ __launch_bounds__(256)
void k_gather(const float* __restrict__ out_in, const int* __restrict__ inv,
              float* __restrict__ o32, u16* __restrict__ obf) {
  __shared__ float tile[32][33];
  int b = blockIdx.z;
  int tr0 = blockIdx.x * 32, s0 = blockIdx.y * 32;
  int tx = threadIdx.x & 31, ty = threadIdx.x >> 5;
  int ntr = TR_ - tr0; if (ntr > 32) ntr = 32;
  for (int i = ty; i < 32; i += 8)
    tile[i][tx] = (tx < ntr) ? out_in[((size_t)b * S_ + s0 + i) * TR_ + tr0 + tx] : 0.f;
  __syncthreads();
  for (int r = ty; r < ntr; r += 8) {
    int t = inv[tr0 + r];
    size_t off = ((size_t)b * TR_ + t) * S_ + s0 + tx;
    float v = tile[tx][r];
    o32[off] = v;
    obf[off] = f2bf(v);
  }
}

// ---------- per-token gating (no atomics) ----------
__global__ __launch_bounds__(256)
void k_gates(const float* __restrict__ o32, const float* __restrict__ temb,
             const float* __restrict__ Wg, const float* __restrict__ bg,
             const float* __restrict__ w2buf, float* __restrict__ gf,
             float* __restrict__ zbuf) {
  int n = blockIdx.x;
  int b = n / TR_, t = n % TR_;
  int typ = (t < 228) ? 0 : (t < 519) ? 1 : (t < 1286) ? 2 : 3;
  int tid = threadIdx.x;
  const float* orow = o32 + (size_t)n * S_;
  const float* trow = temb + typ * S_;
  const float* W0 = Wg + (size_t)(2 * typ) * S_ * 8;

  float acc[16];
#pragma unroll
  for (int k = 0; k < 16; ++k) acc[k] = 0.f;
  for (int s = tid; s < S_; s += 256) {
    float ov = orow[s] + trow[s];
    const float4* wa = (const float4*)(W0 + s * 8);
    const float4* wb = (const float4*)(W0 + 7168 + s * 8);
    float4 a0 = wa[0], a1 = wa[1], b0 = wb[0], b1 = wb[1];
    acc[0]  += ov * a0.x; acc[1]  += ov * a0.y; acc[2]  += ov * a0.z; acc[3]  += ov * a0.w;
    acc[4]  += ov * a1.x; acc[5]  += ov * a1.y; acc[6]  += ov * a1.z; acc[7]  += ov * a1.w;
    acc[8]  += ov * b0.x; acc[9]  += ov * b0.y; acc[10] += ov * b0.z; acc[11] += ov * b0.w;
    acc[12] += ov * b1.x; acc[13] += ov * b1.y; acc[14] += ov * b1.z; acc[15] += ov * b1.w;
  }
#pragma unroll
  for (int k = 0; k < 16; ++k)
#pragma unroll
    for (int m = 1; m < 64; m <<= 1) acc[k] += __shfl_xor(acc[k], m, 64);

  __shared__ float wsum[4][16];
  __shared__ float lgsh[16];
  int w = tid >> 6, lane = tid & 63;
  if (lane == 0)
#pragma unroll
    for (int k = 0; k < 16; ++k) wsum[w][k] = acc[k];
  __syncthreads();
  if (tid < 16)
    lgsh[tid] = wsum[0][tid] + wsum[1][tid] + wsum[2][tid] + wsum[3][tid]
              + bg[(2 * typ + (tid >> 3)) * 8 + (tid & 7)];
  __syncthreads();

  if (tid == 0) {
    float g[8];
    for (int k = 0; k < 8; ++k) g[k] = 0.f;
    float zs[2];
    for (int j = 0; j < 2; ++j) {
      float l[8]; float ss = 0.f;
      for (int k = 0; k < 8; ++k) {
        float v = lgsh[j * 8 + k];
        v = v > 0.f ? v : 0.01f * v;
        l[k] = v; ss += v * v;
      }
      zs[j] = ss;
      int i0 = 0;
      for (int k = 1; k < 8; ++k) if (l[k] > l[i0]) i0 = k;
      int i1 = -1;
      for (int k = 0; k < 8; ++k) { if (k == i0) continue; if (i1 < 0 || l[k] > l[i1]) i1 = k; }
      int i2 = -1;
      for (int k = 0; k < 8; ++k) { if (k == i0 || k == i1) continue; if (i2 < 0 || l[k] > l[i2]) i2 = k; }
      float p1 = expf(l[i1] - l[i0]), p2 = expf(l[i2] - l[i0]);
      float den = 1.f + p1 + p2;
      float w2 = w2buf[b * 8 + 2 * typ + j];
      g[i0] += w2 / den; g[i1] += w2 * p1 / den; g[i2] += w2 * p2 / den;
    }
    float* gfp = gf + (size_t)n * 8;
    for (int k = 0; k < 8; ++k) gfp[k] = g[k];
    zbuf[n * 2 + 0] = zs[0];
    zbuf[n * 2 + 1] = zs[1];
  }
}

// ---------- segment reductions ----------
__global__ __launch_bounds__(256)
void k_reduce_gates(const float* __restrict__ gf, const float* __restrict__ zbuf,
                    float* __restrict__ allg, float* __restrict__ zsum) {
  __shared__ float red[256];
  const int s0a[4] = {0, 228, 519, 1286};
  const int cta[4] = {228, 291, 767, 357};
  int blk = blockIdx.x, tid = threadIdx.x;
  float s = 0.f;
  if (blk < 32) {
    int typ = blk >> 3, e = blk & 7;
    int s0 = s0a[typ], cnt = cta[typ];
    for (int i = tid; i < 2 * cnt; i += 256) {
      int bb = i / cnt, tt = s0 + i % cnt;
      s += gf[(size_t)(bb * TR_ + tt) * 8 + e];
    }
  } else {
    int idx = blk - 32, typ = idx >> 1, j = idx & 1;
    int s0 = s0a[typ], cnt = cta[typ];
    for (int i = tid; i < 2 * cnt; i += 256) {
      int bb = i / cnt, tt = s0 + i % cnt;
      s += zbuf[(size_t)(bb * TR_ + tt) * 2 + j];
    }
  }
  red[tid] = s; __syncthreads();
  for (int st = 128; st > 0; st >>= 1) { if (tid < st) red[tid] += red[tid + st]; __syncthreads(); }
  if (tid == 0) {
    if (blk < 32) allg[blk] = red[0];
    else          zsum[blk - 32] = red[0];
  }
}

// ---------- tiled transpose f32 -> bf16 with output-row padding ----------
__global__ __launch_bounds__(256)
void k_transpose(const float* __restrict__ W, u16* __restrict__ Wt,
                 int R, int C, int ldo, size_t eo) {
  __shared__ float tile[32][33];
  int e = blockIdx.z;
  const float* Wp = W + (size_t)e * R * C;
  u16* Wtp = Wt + (size_t)e * eo;
  int c0 = blockIdx.x * 32, r0 = blockIdx.y * 32;
  int tx = threadIdx.x & 31, ty = threadIdx.x >> 5;
  for (int i = ty; i < 32; i += 8)
    tile[i][tx] = (c0 + tx < C) ? Wp[(size_t)(r0 + i) * C + c0 + tx] : 0.f;
  __syncthreads();
  for (int i = ty; i < 32; i += 8) Wtp[(size_t)(c0 + i) * ldo + r0 + tx] = f2bf(tile[tx][i]);
}

// ---------- 256x256x64 8-wave GEMM — m201 phase sandwich (round-12 change) ----------
// Each phase: [ds_reads issue][stage issue] -> s_barrier -> lgkmcnt(0) -> MFMA -> bar.
// Reads issue BEFORE the barrier so the LDS unit drains them during barrier slack
// (m233 mechanism); publishes (counted vmcnt + barrier) shifted one phase EARLY so
// next phase's reads are legal at phase start. All waits vmcnt(4) — never drains.
// Peel: 4/2/0. Fragment/staging/swizzle byte-identical to the round-9 kernel.
template <int MODE>
__global__ __launch_bounds__(512, 2)
void k_gemm8(const u16* __restrict__ A, const u16* __restrict__ Bt,
             int K, int lda, int ldb,
             const float* __restrict__ gf, const float* __restrict__ bias,
             u16* __restrict__ H, float* __restrict__ ypart, int P) {
  __shared__ __align__(16) u16 lds[2 * 32768];   // [buf][A:16384|B:16384] u16
  const int tid = threadIdx.x;
  const int lane = tid & 63;
  const int wid = tid >> 6;
  const int wr = wid >> 2, wc = wid & 3;

  int bx, by, bz = 0;
  if (MODE == 1) {
    int f = blockIdx.y * 56 + blockIdx.x;            // 728 = 8*91
    f = (f & 7) * 91 + (f >> 3);
    by = f / 56; bx = f % 56;
  } else {
    int f = blockIdx.z * 52 + blockIdx.y * 4 + blockIdx.x;  // 52P, P even
    int n8 = (52 * P) >> 3;
    f = (f & 7) * n8 + (f >> 3);
    bz = f / 52; int r = f % 52;
    by = r / 4; bx = r % 4;
  }

  int kt0 = 0, ktN = K >> 6;
  if (MODE == 2) {
    int nt = K >> 6;
    kt0 = (bz * nt) / P; ktN = ((bz + 1) * nt) / P;
  }
  const int NT = ktN - kt0;

  const u16* Ag = A + (size_t)(by * 256) * lda;
  const u16* Bg = Bt + (size_t)(bx * 256) * ldb;

#define SA(buf, g, k0)                                                          \
  { _Pragma("unroll")                                                           \
    for (int q = 0; q < 2; ++q) {                                               \
      const int br = q * 128 + (g) * 64 + wid * 8;                              \
      const int row = br + (lane >> 3);                                         \
      gload16(Ag + (size_t)row * lda + (((lane & 7) ^ (lane >> 3)) << 3) + (k0),\
              lds + (buf) * 32768 + br * 64 + lane * 8);                        \
    } }
#define SB(buf, g, k0)                                                          \
  { _Pragma("unroll")                                                           \
    for (int q = 0; q < 2; ++q) {                                               \
      const int sI = q * 8 + wid;                                               \
      const int br = (sI >> 2) * 64 + (g) * 32 + (sI & 3) * 8;                  \
      const int row = br + (lane >> 3);                                         \
      gload16(Bg + (size_t)row * ldb + (((lane & 7) ^ (lane >> 3)) << 3) + (k0),\
              lds + (buf) * 32768 + 16384 + br * 64 + lane * 8);                \
    } }

  const int l15 = lane & 15, l16 = lane >> 4, l7 = lane & 7;
  const int swz0 = (l16 ^ l7) << 3;
  const int swz1 = ((4 + l16) ^ l7) << 3;
  const int rA = (wr * 128 + l15) * 64;
  const int rB = (wc * 64 + l15) * 64;

  f32x4 acc[8][4] = {};
  bf16x8 aF[4][2], b0F[2][2], b1F[2][2];

#define READ_A0  _Pragma("unroll") for (int i = 0; i < 4; ++i) {               \
    aF[i][0] = *(const bf16x8*)(lA + rA + i * 1024 + swz0);                    \
    aF[i][1] = *(const bf16x8*)(lA + rA + i * 1024 + swz1); }
#define READ_A1  _Pragma("unroll") for (int i = 0; i < 4; ++i) {               \
    aF[i][0] = *(const bf16x8*)(lA + rA + (i + 4) * 1024 + swz0);              \
    aF[i][1] = *(const bf16x8*)(lA + rA + (i + 4) * 1024 + swz1); }
#define READ_B0  _Pragma("unroll") for (int j = 0; j < 2; ++j) {               \
    b0F[j][0] = *(const bf16x8*)(lB + rB + j * 1024 + swz0);                   \
    b0F[j][1] = *(const bf16x8*)(lB + rB + j * 1024 + swz1); }
#define READ_B1  _Pragma("unroll") for (int j = 0; j < 2; ++j) {               \
    b1F[j][0] = *(const bf16x8*)(lB + rB + (j + 2) * 1024 + swz0);             \
    b1F[j][1] = *(const bf16x8*)(lB + rB + (j + 2) * 1024 + swz1); }
#define MFMA16(IB, JB, BF)                                                     \
  __builtin_amdgcn_s_setprio(1);                                               \
  _Pragma("unroll") for (int i = 0; i < 4; ++i)                                \
  _Pragma("unroll") for (int j = 0; j < 2; ++j) {                              \
    acc[i + IB][j + JB] = __builtin_amdgcn_mfma_f32_16x16x32_bf16(aF[i][0], BF[j][0], acc[i + IB][j + JB], 0, 0, 0); \
    acc[i + IB][j + JB] = __builtin_amdgcn_mfma_f32_16x16x32_bf16(aF[i][1], BF[j][1], acc[i + IB][j + JB], 0, 0, 0); \
  }                                                                            \
  __builtin_amdgcn_s_setprio(0);
#define LGKM0                                                \
  asm volatile("s_waitcnt lgkmcnt(0)" ::: "memory");         \
  __builtin_amdgcn_sched_barrier(0);
#define VBAR(N)                                              \
  asm volatile("s_waitcnt vmcnt(" #N ")" ::: "memory");      \
  __builtin_amdgcn_s_barrier();

  // prologue: tile kt0, issue order U0=A0, U1=B0, U2=B1, U3=A1; publish U0,U1
  { const int k0 = kt0 << 6; SA(0, 0, k0) SB(0, 0, k0) SB(0, 1, k0) SA(0, 1, k0) }
  VBAR(4)

  int cur = 0;
  for (int t = 0; t < NT - 1; ++t) {
    const u16* lA = lds + cur * 32768;
    const u16* lB = lA + 16384;
    const int nk0 = (kt0 + t + 1) << 6;
    const int nxt = cur ^ 1;
    // P1: read A0,B0 | stage U0' | bar | lgkm0 | Q00 | publish U2 (vmcnt4+bar)
    READ_A0 READ_B0
    SA(nxt, 0, nk0)
    __builtin_amdgcn_s_barrier();
    LGKM0
    MFMA16(0, 0, b0F)
    VBAR(4)
    // P2: read B1 | stage U1' | bar | lgkm0 | Q01 | publish U3 (vmcnt4+bar)
    READ_B1
    SB(nxt, 0, nk0)
    __builtin_amdgcn_s_barrier();
    LGKM0
    MFMA16(0, 2, b1F)
    VBAR(4)
    // P3: read A1 | stage U2' | bar | lgkm0 | Q11 | bar
    READ_A1
    SB(nxt, 1, nk0)
    __builtin_amdgcn_s_barrier();
    LGKM0
    MFMA16(4, 2, b1F)
    __builtin_amdgcn_s_barrier();
    // P4: stage U3' | Q10 (regs only) | publish U0',U1' (vmcnt4+bar)
    SA(nxt, 1, nk0)
    MFMA16(4, 0, b0F)
    VBAR(4)
    cur ^= 1;
  }
  // peel last tile: draining publishes 2 -> 0
  {
    const u16* lA = lds + cur * 32768;
    const u16* lB = lA + 16384;
    READ_A0 READ_B0
    __builtin_amdgcn_s_barrier();
    LGKM0
    MFMA16(0, 0, b0F)
    VBAR(2)
    READ_B1
    LGKM0
    MFMA16(0, 2, b1F)
    VBAR(0)
    READ_A1
    LGKM0
    MFMA16(4, 2, b1F)
    MFMA16(4, 0, b0F)
  }
#undef SA
#undef SB
#undef READ_A0
#undef READ_A1
#undef READ_B0
#undef READ_B1
#undef MFMA16
#undef LGKM0
#undef VBAR

  // ---- epilogue ----
  if (MODE == 1) {
    const int e = bx / 7;                 // 1792 = 7*256: tile within one expert
#pragma unroll
    for (int j = 0; j < 4; ++j) {
      const int col = bx * 256 + wc * 64 + j * 16 + l15;
      const float bia = bias[col];
#pragma unroll
      for (int i = 0; i < 8; ++i)
#pragma unroll
        for (int r = 0; r < 4; ++r) {
          const int row = by * 256 + wr * 128 + i * 16 + l16 * 4 + r;
          float v = acc[i][j][r] + bia;
          v = v > 0.f ? v : 0.f;
          H[(size_t)row * 14336 + col] = f2bf(v * gf[row * 8 + e]);
        }
    }
  } else {
    float* yp = ypart + (size_t)bz * ((size_t)MP_ * 1024);
#pragma unroll
    for (int j = 0; j < 4; ++j) {
      const int col = bx * 256 + wc * 64 + j * 16 + l15;
#pragma unroll
      for (int i = 0; i < 8; ++i)
#pragma unroll
        for (int r = 0; r < 4; ++r) {
          const int row = by * 256 + wr * 128 + i * 16 + l16 * 4 + r;
          yp[(size_t)row * 1024 + col] = acc[i][j][r];
        }
    }
  }
}

// ---------- reduce split-K partials + gated b2 bias, TRANSPOSED output ----------
__global__ __launch_bounds__(256)
void k_reduce_yT(const float* __restrict__ yp, int P,
                 const float* __restrict__ gf, const float* __restrict__ b2,
                 float* __restrict__ yT) {
  __shared__ float tile[32][33];
  int b = blockIdx.z;
  int t0 = blockIdx.x * 32, s0 = blockIdx.y * 32;
  int tx = threadIdx.x & 31, ty = threadIdx.x >> 5;
  int ntv = TR_ - t0; if (ntv > 32) ntv = 32;
  for (int r = ty; r < 32; r += 8) {
    float acc = 0.f;
    if (r < ntv) {
      size_t n = (size_t)b * TR_ + t0 + r;
      size_t base = n * 1024 + s0 + tx;
      for (int p = 0; p < P; ++p) acc += yp[(size_t)p * ((size_t)MP_ * 1024) + base];
      const float* g = gf + n * 8;
#pragma unroll
      for (int e = 0; e < 8; ++e) acc += g[e] * b2[e * S_ + s0 + tx];
    }
    tile[r][tx] = acc;
  }
  __syncthreads();
  for (int i = ty; i < 32; i += 8)
    if (tx < ntv)
      yT[((size_t)b * S_ + s0 + i) * TR_ + t0 + tx] = tile[tx][i];
}

// ---------- scatter: dout[b,s,tr] = out[b,s,tr] + yT[b,s,inv[tr]] ----------
__global__ void k_scatter(const float* __restrict__ yT, const float* __restrict__ out_in,
                          const int* __restrict__ inv, float* __restrict__ dout) {
  int i = blockIdx.x * 256 + threadIdx.x;   // < B*S*TR = 2944256
  int tr = i % TR_;
  dout[i] = out_in[i] + yT[(size_t)(i - tr) + inv[tr]];
}

// ---------- finalize ----------
__global__ void k_finalize(const float* __restrict__ allg, const float* __restrict__ zsum,
                           const float* __restrict__ zpart, float* __restrict__ dout) {
  int tid = threadIdx.x;
  if (tid < 32) dout[2944256 + tid] = allg[tid];
  if (tid == 32) {
    float z = *zpart;
    const int Ts[4] = {228, 291, 767, 357};
    for (int i = 0; i < 4; ++i)
      for (int j = 0; j < 2; ++j)
        z += zsum[i * 2 + j] / (float)(2 * Ts[i] * 8);
    dout[2944288] = z;
    dout[2944289] = 0.f;
  }
}

extern "C" void kernel_launch(void* const* d_in, const int* in_sizes, int n_in,
                              void* d_out, int out_size, void* d_ws, size_t ws_size,
                              hipStream_t stream) {
  const float* x         = (const float*)d_in[0];
  const float* out_in    = (const float*)d_in[1];
  const float* embedding = (const float*)d_in[2];
  const int*   index     = (const int*)d_in[3];
  const float* Wsel      = (const float*)d_in[4];
  const float* bsel      = (const float*)d_in[5];
  const float* Wemb      = (const float*)d_in[6];
  const float* bemb      = (const float*)d_in[7];
  const float* Wg        = (const float*)d_in[8];
  const float* bg        = (const float*)d_in[9];
  const float* temb      = (const float*)d_in[10];
  const float* W1        = (const float*)d_in[11];
  const float* b1        = (const float*)d_in[12];
  const float* W2        = (const float*)d_in[13];
  const float* b2        = (const float*)d_in[14];
  float* dout = (float*)d_out;

  char* ws = (char*)d_ws;
  float* allg  = (float*)(ws + 0);
  float* zsum  = (float*)(ws + 128);
  float* zpart = (float*)(ws + 160);
  float* w2buf = (float*)(ws + 192);
  int*   inv   = (int*)(ws + 256);
  float* xmean = (float*)(ws + 8192);
  float* gf    = (float*)(ws + 32768);       // MP*8 f        -> ends 139264
  float* o32   = (float*)(ws + 139264);      // MP*896 f      -> ends 12066816 (reused as yT)
  float* yT    = o32;
  float* zbuf  = (float*)(ws + 139264 + (size_t)NTOK_ * S_ * 4);  // pad-row overlay
  u16*   obf   = (u16*)(ws + 12066816);      // MP*896 bf16   -> ends 18030592
  u16*   w1t   = (u16*)(ws + 18030592);      // 14336*896 bf16 -> ends 43720704
  u16*   w2t   = (u16*)(ws + 43720704);      // 1024*14336 bf16 (padded) -> ends 73080832
  u16*   Hb    = (u16*)(ws + 73080832);      // MP*14336 bf16  -> ends 168501248

  const size_t HIGH = 168501248ull, YPSZ = (size_t)MP_ * 1024 * 4;  // 13,631,488
  int P; float* ypart = (float*)(ws + HIGH);
  if      (ws_size >= HIGH + 8 * YPSZ) P = 8;
  else if (ws_size >= HIGH + 6 * YPSZ) P = 6;
  else if (ws_size >= HIGH + 4 * YPSZ) P = 4;
  else                                 P = 2;

  k_init<<<147, 256, 0, stream>>>(index, inv, xmean, o32, obf, gf);
  k_reduce_x<<<dim3(24, 4), 256, 0, stream>>>(x, xmean);
  k_small_gates<<<1, 256, 0, stream>>>(xmean, Wsel, bsel, embedding, Wemb, bemb,
                                       w2buf, zpart, dout + 2944290);
  k_gather<<<dim3(52, 28, 2), 256, 0, stream>>>(out_in, inv, o32, obf);
  k_gates<<<NTOK_, 256, 0, stream>>>(o32, temb, Wg, bg, w2buf, gf, zbuf);
  k_reduce_gates<<<40, 256, 0, stream>>>(gf, zbuf, allg, zsum);

  // GEMM1: H' = gf .* relu(obf @ W1^T + b1)   [M=3328, N=14336, K=896]
  k_transpose<<<dim3(56, 28, 8), 256, 0, stream>>>(W1, w1t, 896, 1792, 896, (size_t)1605632);
  k_gemm8<1><<<dim3(56, 13), 512, 0, stream>>>(
      obf, w1t, 896, 896, 896, gf, b1, Hb, nullptr, 0);

  // GEMM2: ypart[z] = H' @ W2flat^T chunk  [M=3328, N=896(pad 1024), K=14336 split-P]
  k_transpose<<<dim3(32, 56, 8), 256, 0, stream>>>(W2, w2t, 1792, 896, 14336, (size_t)1792);
  k_gemm8<2><<<dim3(4, 13, P), 512, 0, stream>>>(
      Hb, w2t, 14336, 14336, 14336, nullptr, nullptr, nullptr, ypart, P);
  k_reduce_yT<<<dim3(52, 28, 2), 256, 0, stream>>>(ypart, P, gf, b2, yT);

  k_scatter<<<11501, 256, 0, stream>>>(yT, out_in, inv, dout);
  k_finalize<<<1, 64, 0, stream>>>(allg, zsum, zpart, dout);
}

// Round 15
// 393.401 us; speedup vs baseline: 1.1407x; 1.1407x over previous
//
#include <hip/hip_runtime.h>

typedef unsigned short u16;
typedef unsigned int u32;
typedef __bf16 bf16x8 __attribute__((ext_vector_type(8)));
typedef float f32x4 __attribute__((ext_vector_type(4)));

#define S_    896
#define TR_   1643
#define NTOK_ 3286
#define MP_   3328   // 26*128 padded token rows

// ---------- helpers ----------
__device__ __forceinline__ u16 f2bf(float f) {
  u32 u = __builtin_bit_cast(u32, f);
  u = (u + 0x7FFFu + ((u >> 16) & 1u)) >> 16;   // RNE
  return (u16)u;
}

__device__ __forceinline__ void gload16(const void* g, void* l) {
  __builtin_amdgcn_global_load_lds(
      (const __attribute__((address_space(1))) u32*)g,
      (__attribute__((address_space(3))) u32*)l, 16, 0, 0);
}

// ---------- init: inv perm, xmean zero, pad-row zero (o32/obf/gf) ----------
__global__ void k_init(const int* __restrict__ index, int* __restrict__ inv,
                       float* __restrict__ xmean, float* __restrict__ o32,
                       u16* __restrict__ obf, float* __restrict__ gf) {
  int i = blockIdx.x * 256 + threadIdx.x;
  if (i < TR_) inv[index[i]] = i;
  if (i < 6144) xmean[i] = 0.f;
  if (i < 336) gf[(size_t)NTOK_ * 8 + i] = 0.f;         // pad-row gates
  o32[(size_t)NTOK_ * S_ + i] = 0.f;                    // pad rows (also zbuf init)
  obf[(size_t)NTOK_ * S_ + i] = 0;                      // GEMM1 A pad rows
}

// ---------- xmean ----------
__global__ void k_reduce_x(const float* __restrict__ x, float* __restrict__ xmean) {
  int i = blockIdx.x * 256 + threadIdx.x;
  int b = i / 3072, d = i % 3072;
  int s0 = blockIdx.y * 224;
  const float* p = x + (size_t)b * S_ * 3072 + (size_t)s0 * 3072 + d;
  float s = 0.f;
  for (int t = 0; t < 224; ++t) s += p[(size_t)t * 3072];
  atomicAdd(&xmean[i], s * (1.f / (float)S_));
}

// ---------- small gating, stage 1: 24 parallel dots (round-14: was 1 serial block) ----------
// blk<16: gl[b][g] = xmean[b] . Wsel[:,g] + bsel[g];  blk>=16: el[g] = emb . Wemb[:,g] + bemb[g]
__global__ __launch_bounds__(256)
void k_small_dots(const float* __restrict__ xmean,
                  const float* __restrict__ Wsel, const float* __restrict__ bsel,
                  const float* __restrict__ emb,  const float* __restrict__ Wemb,
                  const float* __restrict__ bemb, float* __restrict__ glel) {
  __shared__ float red[256];
  int blk = blockIdx.x, tid = threadIdx.x;
  float s = 0.f;
  if (blk < 16) {
    int b = blk >> 3, g = blk & 7;
    for (int d = tid; d < 3072; d += 256) s += xmean[b * 3072 + d] * Wsel[d * 8 + g];
  } else {
    int g = blk - 16;
    for (int d = tid; d < 1536; d += 256) s += emb[d] * Wemb[d * 8 + g];
  }
  red[tid] = s; __syncthreads();
  for (int st = 128; st > 0; st >>= 1) { if (tid < st) red[tid] += red[tid + st]; __syncthreads(); }
  if (tid == 0) glel[blk] = red[0] + (blk < 16 ? bsel[blk & 7] : bemb[blk - 16]);
}

// ---------- small gating, stage 2: tiny tail (w2buf, weights out, zpart) ----------
__global__ void k_small_tail(const float* __restrict__ glel,
                             float* __restrict__ w2buf, float* __restrict__ zpart,
                             float* __restrict__ outw) {
  if (threadIdx.x != 0) return;
  const float* gl = glel;        // [b*8+g]
  const float* el = glel + 16;   // [g]
  float zp = 0.f;
  for (int i = 0; i < 4; ++i) {
    float e0 = el[2 * i], e1 = el[2 * i + 1];
    float m = fmaxf(e0, e1);
    float x0 = expf(e0 - m), x1 = expf(e1 - m);
    float den = x0 + x1;
    float se0 = x0 / den, se1 = x1 / den;
    zp += (e0 * e0 + e1 * e1) * 0.5f;
    float tsq = 0.f;
    for (int b = 0; b < 2; ++b) {
      float t0 = gl[b * 8 + 2 * i], t1 = gl[b * 8 + 2 * i + 1];
      tsq += t0 * t0 + t1 * t1;
      float mm = fmaxf(t0, t1);
      float y0 = expf(t0 - mm), y1 = expf(t1 - mm);
      float dd = y0 + y1;
      float w0 = (y0 / dd + se0) * 0.5f, w1 = (y1 / dd + se1) * 0.5f;
      w2buf[b * 8 + 2 * i] = w0; w2buf[b * 8 + 2 * i + 1] = w1;
      outw[b * 8 + 2 * i]  = w0; outw[b * 8 + 2 * i + 1]  = w1;
    }
    zp += tsq * 0.25f;
  }
  *zpart = zp;
}

// ---------- gather (LDS-tiled transpose, both sides coalesced) ----------
__global__ __launch_bounds__(256)
void k_gather(const float* __restrict__ out_in, const int* __restrict__ inv,
              float* __restrict__ o32, u16* __restrict__ obf) {
  __shared__ float tile[32][33];
  int b = blockIdx.z;
  int tr0 = blockIdx.x * 32, s0 = blockIdx.y * 32;
  int tx = threadIdx.x & 31, ty = threadIdx.x >> 5;
  int ntr = TR_ - tr0; if (ntr > 32) ntr = 32;
  for (int i = ty; i < 32; i += 8)
    tile[i][tx] = (tx < ntr) ? out_in[((size_t)b * S_ + s0 + i) * TR_ + tr0 + tx] : 0.f;
  __syncthreads();
  for (int r = ty; r < ntr; r += 8) {
    int t = inv[tr0 + r];
    size_t off = ((size_t)b * TR_ + t) * S_ + s0 + tx;
    float v = tile[tx][r];
    o32[off] = v;
    obf[off] = f2bf(v);
  }
}

// ---------- per-token gating (no atomics) ----------
__global__ __launch_bounds__(256)
void k_gates(const float* __restrict__ o32, const float* __restrict__ temb,
             const float* __restrict__ Wg, const float* __restrict__ bg,
             const float* __restrict__ w2buf, float* __restrict__ gf,
             float* __restrict__ zbuf) {
  int n = blockIdx.x;
  int b = n / TR_, t = n % TR_;
  int typ = (t < 228) ? 0 : (t < 519) ? 1 : (t < 1286) ? 2 : 3;
  int tid = threadIdx.x;
  const float* orow = o32 + (size_t)n * S_;
  const float* trow = temb + typ * S_;
  const float* W0 = Wg + (size_t)(2 * typ) * S_ * 8;

  float acc[16];
#pragma unroll
  for (int k = 0; k < 16; ++k) acc[k] = 0.f;
  for (int s = tid; s < S_; s += 256) {
    float ov = orow[s] + trow[s];
    const float4* wa = (const float4*)(W0 + s * 8);
    const float4* wb = (const float4*)(W0 + 7168 + s * 8);
    float4 a0 = wa[0], a1 = wa[1], b0 = wb[0], b1 = wb[1];
    acc[0]  += ov * a0.x; acc[1]  += ov * a0.y; acc[2]  += ov * a0.z; acc[3]  += ov * a0.w;
    acc[4]  += ov * a1.x; acc[5]  += ov * a1.y; acc[6]  += ov * a1.z; acc[7]  += ov * a1.w;
    acc[8]  += ov * b0.x; acc[9]  += ov * b0.y; acc[10] += ov * b0.z; acc[11] += ov * b0.w;
    acc[12] += ov * b1.x; acc[13] += ov * b1.y; acc[14] += ov * b1.z; acc[15] += ov * b1.w;
  }
#pragma unroll
  for (int k = 0; k < 16; ++k)
#pragma unroll
    for (int m = 1; m < 64; m <<= 1) acc[k] += __shfl_xor(acc[k], m, 64);

  __shared__ float wsum[4][16];
  __shared__ float lgsh[16];
  int w = tid >> 6, lane = tid & 63;
  if (lane == 0)
#pragma unroll
    for (int k = 0; k < 16; ++k) wsum[w][k] = acc[k];
  __syncthreads();
  if (tid < 16)
    lgsh[tid] = wsum[0][tid] + wsum[1][tid] + wsum[2][tid] + wsum[3][tid]
              + bg[(2 * typ + (tid >> 3)) * 8 + (tid & 7)];
  __syncthreads();

  if (tid == 0) {
    float g[8];
    for (int k = 0; k < 8; ++k) g[k] = 0.f;
    float zs[2];
    for (int j = 0; j < 2; ++j) {
      float l[8]; float ss = 0.f;
      for (int k = 0; k < 8; ++k) {
        float v = lgsh[j * 8 + k];
        v = v > 0.f ? v : 0.01f * v;
        l[k] = v; ss += v * v;
      }
      zs[j] = ss;
      int i0 = 0;
      for (int k = 1; k < 8; ++k) if (l[k] > l[i0]) i0 = k;
      int i1 = -1;
      for (int k = 0; k < 8; ++k) { if (k == i0) continue; if (i1 < 0 || l[k] > l[i1]) i1 = k; }
      int i2 = -1;
      for (int k = 0; k < 8; ++k) { if (k == i0 || k == i1) continue; if (i2 < 0 || l[k] > l[i2]) i2 = k; }
      float p1 = expf(l[i1] - l[i0]), p2 = expf(l[i2] - l[i0]);
      float den = 1.f + p1 + p2;
      float w2 = w2buf[b * 8 + 2 * typ + j];
      g[i0] += w2 / den; g[i1] += w2 * p1 / den; g[i2] += w2 * p2 / den;
    }
    float* gfp = gf + (size_t)n * 8;
    for (int k = 0; k < 8; ++k) gfp[k] = g[k];
    zbuf[n * 2 + 0] = zs[0];
    zbuf[n * 2 + 1] = zs[1];
  }
}

// ---------- segment reductions ----------
__global__ __launch_bounds__(256)
void k_reduce_gates(const float* __restrict__ gf, const float* __restrict__ zbuf,
                    float* __restrict__ allg, float* __restrict__ zsum) {
  __shared__ float red[256];
  const int s0a[4] = {0, 228, 519, 1286};
  const int cta[4] = {228, 291, 767, 357};
  int blk = blockIdx.x, tid = threadIdx.x;
  float s = 0.f;
  if (blk < 32) {
    int typ = blk >> 3, e = blk & 7;
    int s0 = s0a[typ], cnt = cta[typ];
    for (int i = tid; i < 2 * cnt; i += 256) {
      int bb = i / cnt, tt = s0 + i % cnt;
      s += gf[(size_t)(bb * TR_ + tt) * 8 + e];
    }
  } else {
    int idx = blk - 32, typ = idx >> 1, j = idx & 1;
    int s0 = s0a[typ], cnt = cta[typ];
    for (int i = tid; i < 2 * cnt; i += 256) {
      int bb = i / cnt, tt = s0 + i % cnt;
      s += zbuf[(size_t)(bb * TR_ + tt) * 2 + j];
    }
  }
  red[tid] = s; __syncthreads();
  for (int st = 128; st > 0; st >>= 1) { if (tid < st) red[tid] += red[tid + st]; __syncthreads(); }
  if (tid == 0) {
    if (blk < 32) allg[blk] = red[0];
    else          zsum[blk - 32] = red[0];
  }
}

// ---------- tiled transpose f32 -> bf16 with output-row padding ----------
__global__ __launch_bounds__(256)
void k_transpose(const float* __restrict__ W, u16* __restrict__ Wt,
                 int R, int C, int ldo, size_t eo) {
  __shared__ float tile[32][33];
  int e = blockIdx.z;
  const float* Wp = W + (size_t)e * R * C;
  u16* Wtp = Wt + (size_t)e * eo;
  int c0 = blockIdx.x * 32, r0 = blockIdx.y * 32;
  int tx = threadIdx.x & 31, ty = threadIdx.x >> 5;
  for (int i = ty; i < 32; i += 8)
    tile[i][tx] = (c0 + tx < C) ? Wp[(size_t)(r0 + i) * C + c0 + tx] : 0.f;
  __syncthreads();
  for (int i = ty; i < 32; i += 8) Wtp[(size_t)(c0 + i) * ldo + r0 + tx] = f2bf(tile[tx][i]);
}

// ---------- 256x256x64 8-wave COUNTED-VMCNT phase GEMM (round-9 schedule, verbatim) ----------
// Three sync variants (r9 counted / r10 read-ahead / r12 sandwich) all measure
// ~30% MfmaUtil = the 2-phase 256^2 plateau (m230/m248: 655-682 TF). r9 is the
// fastest of the three; GEMM sync is frozen here per the round-12 pre-commitment.
template <int MODE>
__global__ __launch_bounds__(512, 2)
void k_gemm8(const u16* __restrict__ A, const u16* __restrict__ Bt,
             int K, int lda, int ldb,
             const float* __restrict__ gf, const float* __restrict__ bias,
             u16* __restrict__ H, float* __restrict__ ypart, int P) {
  __shared__ __align__(16) u16 lds[2 * 32768];   // [buf][A:16384|B:16384] u16
  const int tid = threadIdx.x;
  const int lane = tid & 63;
  const int wid = tid >> 6;
  const int wr = wid >> 2, wc = wid & 3;

  int bx, by, bz = 0;
  if (MODE == 1) {
    int f = blockIdx.y * 56 + blockIdx.x;            // 728 = 8*91
    f = (f & 7) * 91 + (f >> 3);
    by = f / 56; bx = f % 56;
  } else {
    int f = blockIdx.z * 52 + blockIdx.y * 4 + blockIdx.x;  // 52P, P even
    int n8 = (52 * P) >> 3;
    f = (f & 7) * n8 + (f >> 3);
    bz = f / 52; int r = f % 52;
    by = r / 4; bx = r % 4;
  }

  int kt0 = 0, ktN = K >> 6;
  if (MODE == 2) {
    int nt = K >> 6;
    kt0 = (bz * nt) / P; ktN = ((bz + 1) * nt) / P;
  }
  const int NT = ktN - kt0;

  const u16* Ag = A + (size_t)(by * 256) * lda;
  const u16* Bg = Bt + (size_t)(bx * 256) * ldb;

#define SA(buf, g, k0)                                                          \
  { _Pragma("unroll")                                                           \
    for (int q = 0; q < 2; ++q) {                                               \
      const int br = q * 128 + (g) * 64 + wid * 8;                              \
      const int row = br + (lane >> 3);                                         \
      gload16(Ag + (size_t)row * lda + (((lane & 7) ^ (lane >> 3)) << 3) + (k0),\
              lds + (buf) * 32768 + br * 64 + lane * 8);                        \
    } }
#define SB(buf, g, k0)                                                          \
  { _Pragma("unroll")                                                           \
    for (int q = 0; q < 2; ++q) {                                               \
      const int sI = q * 8 + wid;                                               \
      const int br = (sI >> 2) * 64 + (g) * 32 + (sI & 3) * 8;                  \
      const int row = br + (lane >> 3);                                         \
      gload16(Bg + (size_t)row * ldb + (((lane & 7) ^ (lane >> 3)) << 3) + (k0),\
              lds + (buf) * 32768 + 16384 + br * 64 + lane * 8);                \
    } }
#define PSYNC(N)                                             \
  asm volatile("s_waitcnt vmcnt(" #N ")" ::: "memory");      \
  __builtin_amdgcn_s_barrier();                              \
  __builtin_amdgcn_sched_barrier(0);

  const int l15 = lane & 15, l16 = lane >> 4, l7 = lane & 7;
  const int swz0 = (l16 ^ l7) << 3;
  const int swz1 = ((4 + l16) ^ l7) << 3;
  const int rA = (wr * 128 + l15) * 64;
  const int rB = (wc * 64 + l15) * 64;

  f32x4 acc[8][4] = {};
  bf16x8 aF[4][2], b0F[2][2], b1F[2][2];

#define READ_A0  _Pragma("unroll") for (int i = 0; i < 4; ++i) {               \
    aF[i][0] = *(const bf16x8*)(lA + rA + i * 1024 + swz0);                    \
    aF[i][1] = *(const bf16x8*)(lA + rA + i * 1024 + swz1); }
#define READ_A1  _Pragma("unroll") for (int i = 0; i < 4; ++i) {               \
    aF[i][0] = *(const bf16x8*)(lA + rA + (i + 4) * 1024 + swz0);              \
    aF[i][1] = *(const bf16x8*)(lA + rA + (i + 4) * 1024 + swz1); }
#define READ_B0  _Pragma("unroll") for (int j = 0; j < 2; ++j) {               \
    b0F[j][0] = *(const bf16x8*)(lB + rB + j * 1024 + swz0);                   \
    b0F[j][1] = *(const bf16x8*)(lB + rB + j * 1024 + swz1); }
#define READ_B1  _Pragma("unroll") for (int j = 0; j < 2; ++j) {               \
    b1F[j][0] = *(const bf16x8*)(lB + rB + (j + 2) * 1024 + swz0);             \
    b1F[j][1] = *(const bf16x8*)(lB + rB + (j + 2) * 1024 + swz1); }
#define MFMA16(IB, JB, BF)                                                     \
  __builtin_amdgcn_s_setprio(1);                                               \
  _Pragma("unroll") for (int i = 0; i < 4; ++i)                                \
  _Pragma("unroll") for (int j = 0; j < 2; ++j) {                              \
    acc[i + IB][j + JB] = __builtin_amdgcn_mfma_f32_16x16x32_bf16(aF[i][0], BF[j][0], acc[i + IB][j + JB], 0, 0, 0); \
    acc[i + IB][j + JB] = __builtin_amdgcn_mfma_f32_16x16x32_bf16(aF[i][1], BF[j][1], acc[i + IB][j + JB], 0, 0, 0); \
  }                                                                            \
  __builtin_amdgcn_s_setprio(0);

  // prologue: tile kt0, issue order A0,B0,B1,A1 (oldest -> newest)
  { const int k0 = kt0 << 6; SA(0, 0, k0) SB(0, 0, k0) SB(0, 1, k0) SA(0, 1, k0) }

  int cur = 0;
  for (int t = 0; t < NT - 1; ++t) {
    const u16* lA = lds + cur * 32768;
    const u16* lB = lA + 16384;
    const int nk0 = (kt0 + t + 1) << 6;
    // P1: wait A0,B0(t); issue A0,B0(t+1); Q00
    PSYNC(4)
    SA(cur ^ 1, 0, nk0) SB(cur ^ 1, 0, nk0)
    READ_A0 READ_B0
    MFMA16(0, 0, b0F)
    // P2: wait B1(t); issue B1(t+1); Q01
    PSYNC(6)
    SB(cur ^ 1, 1, nk0)
    READ_B1
    MFMA16(0, 2, b1F)
    // P3: wait A1(t); issue A1(t+1); Q11
    PSYNC(6)
    SA(cur ^ 1, 1, nk0)
    READ_A1
    MFMA16(4, 2, b1F)
    // P4: regs only; Q10
    MFMA16(4, 0, b0F)
    cur ^= 1;
  }
  // last tile: peel with draining waits
  {
    const u16* lA = lds + cur * 32768;
    const u16* lB = lA + 16384;
    PSYNC(4)
    READ_A0 READ_B0
    MFMA16(0, 0, b0F)
    PSYNC(2)
    READ_B1
    MFMA16(0, 2, b1F)
    PSYNC(0)
    READ_A1
    MFMA16(4, 2, b1F)
    MFMA16(4, 0, b0F)
  }
#undef SA
#undef SB
#undef PSYNC
#undef READ_A0
#undef READ_A1
#undef READ_B0
#undef READ_B1
#undef MFMA16

  // ---- epilogue ----
  if (MODE == 1) {
    const int e = bx / 7;                 // 1792 = 7*256: tile within one expert
#pragma unroll
    for (int j = 0; j < 4; ++j) {
      const int col = bx * 256 + wc * 64 + j * 16 + l15;
      const float bia = bias[col];
#pragma unroll
      for (int i = 0; i < 8; ++i)
#pragma unroll
        for (int r = 0; r < 4; ++r) {
          const int row = by * 256 + wr * 128 + i * 16 + l16 * 4 + r;
          float v = acc[i][j][r] + bia;
          v = v > 0.f ? v : 0.f;
          H[(size_t)row * 14336 + col] = f2bf(v * gf[row * 8 + e]);
        }
    }
  } else {
    float* yp = ypart + (size_t)bz * ((size_t)MP_ * 1024);
#pragma unroll
    for (int j = 0; j < 4; ++j) {
      const int col = bx * 256 + wc * 64 + j * 16 + l15;
      if (col < 896) {                    // skip N-pad stores (cols 896..1023)
#pragma unroll
        for (int i = 0; i < 8; ++i)
#pragma unroll
          for (int r = 0; r < 4; ++r) {
            const int row = by * 256 + wr * 128 + i * 16 + l16 * 4 + r;
            yp[(size_t)row * 1024 + col] = acc[i][j][r];
          }
      }
    }
  }
}

// ---------- reduce split-K partials + gated b2 bias, TRANSPOSED output ----------
__global__ __launch_bounds__(256)
void k_reduce_yT(const float* __restrict__ yp, int P,
                 const float* __restrict__ gf, const float* __restrict__ b2,
                 float* __restrict__ yT) {
  __shared__ float tile[32][33];
  int b = blockIdx.z;
  int t0 = blockIdx.x * 32, s0 = blockIdx.y * 32;
  int tx = threadIdx.x & 31, ty = threadIdx.x >> 5;
  int ntv = TR_ - t0; if (ntv > 32) ntv = 32;
  for (int r = ty; r < 32; r += 8) {
    float acc = 0.f;
    if (r < ntv) {
      size_t n = (size_t)b * TR_ + t0 + r;
      size_t base = n * 1024 + s0 + tx;
      for (int p = 0; p < P; ++p) acc += yp[(size_t)p * ((size_t)MP_ * 1024) + base];
      const float* g = gf + n * 8;
#pragma unroll
      for (int e = 0; e < 8; ++e) acc += g[e] * b2[e * S_ + s0 + tx];
    }
    tile[r][tx] = acc;
  }
  __syncthreads();
  for (int i = ty; i < 32; i += 8)
    if (tx < ntv)
      yT[((size_t)b * S_ + s0 + i) * TR_ + t0 + tx] = tile[tx][i];
}

// ---------- scatter + fused finalize (round-14: one less launch) ----------
__global__ void k_scatter(const float* __restrict__ yT, const float* __restrict__ out_in,
                          const int* __restrict__ inv, float* __restrict__ dout,
                          const float* __restrict__ allg, const float* __restrict__ zsum,
                          const float* __restrict__ zpart) {
  int i = blockIdx.x * 256 + threadIdx.x;   // < B*S*TR = 2944256 exactly
  int tr = i % TR_;
  dout[i] = out_in[i] + yT[(size_t)(i - tr) + inv[tr]];
  if (blockIdx.x == 0) {
    int tid = threadIdx.x;
    if (tid < 32) dout[2944256 + tid] = allg[tid];
    else if (tid == 32) {
      float z = *zpart;
      const int Ts[4] = {228, 291, 767, 357};
      for (int q = 0; q < 4; ++q)
        for (int j = 0; j < 2; ++j)
          z += zsum[q * 2 + j] / (float)(2 * Ts[q] * 8);
      dout[2944288] = z;
      dout[2944289] = 0.f;
    }
  }
}

extern "C" void kernel_launch(void* const* d_in, const int* in_sizes, int n_in,
                              void* d_out, int out_size, void* d_ws, size_t ws_size,
                              hipStream_t stream) {
  const float* x         = (const float*)d_in[0];
  const float* out_in    = (const float*)d_in[1];
  const float* embedding = (const float*)d_in[2];
  const int*   index     = (const int*)d_in[3];
  const float* Wsel      = (const float*)d_in[4];
  const float* bsel      = (const float*)d_in[5];
  const float* Wemb      = (const float*)d_in[6];
  const float* bemb      = (const float*)d_in[7];
  const float* Wg        = (const float*)d_in[8];
  const float* bg        = (const float*)d_in[9];
  const float* temb      = (const float*)d_in[10];
  const float* W1        = (const float*)d_in[11];
  const float* b1        = (const float*)d_in[12];
  const float* W2        = (const float*)d_in[13];
  const float* b2        = (const float*)d_in[14];
  float* dout = (float*)d_out;

  char* ws = (char*)d_ws;
  float* allg  = (float*)(ws + 0);
  float* zsum  = (float*)(ws + 128);
  float* zpart = (float*)(ws + 160);
  float* w2buf = (float*)(ws + 192);
  int*   inv   = (int*)(ws + 256);           // 1643 i -> ends 6828
  float* glel  = (float*)(ws + 6912);        // 24 f
  float* xmean = (float*)(ws + 8192);
  float* gf    = (float*)(ws + 32768);       // MP*8 f        -> ends 139264
  float* o32   = (float*)(ws + 139264);      // MP*896 f      -> ends 12066816 (reused as yT)
  float* yT    = o32;
  float* zbuf  = (float*)(ws + 139264 + (size_t)NTOK_ * S_ * 4);  // pad-row overlay
  u16*   obf   = (u16*)(ws + 12066816);      // MP*896 bf16   -> ends 18030592
  u16*   w1t   = (u16*)(ws + 18030592);      // 14336*896 bf16 -> ends 43720704
  u16*   w2t   = (u16*)(ws + 43720704);      // 1024*14336 bf16 (padded) -> ends 73080832
  u16*   Hb    = (u16*)(ws + 73080832);      // MP*14336 bf16  -> ends 168501248

  const size_t HIGH = 168501248ull, YPSZ = (size_t)MP_ * 1024 * 4;  // 13,631,488
  int P; float* ypart = (float*)(ws + HIGH);
  if      (ws_size >= HIGH + 8 * YPSZ) P = 8;
  else if (ws_size >= HIGH + 6 * YPSZ) P = 6;
  else if (ws_size >= HIGH + 4 * YPSZ) P = 4;
  else                                 P = 2;

  k_init<<<147, 256, 0, stream>>>(index, inv, xmean, o32, obf, gf);
  k_reduce_x<<<dim3(24, 4), 256, 0, stream>>>(x, xmean);
  k_small_dots<<<24, 256, 0, stream>>>(xmean, Wsel, bsel, embedding, Wemb, bemb, glel);
  k_small_tail<<<1, 64, 0, stream>>>(glel, w2buf, zpart, dout + 2944290);
  k_gather<<<dim3(52, 28, 2), 256, 0, stream>>>(out_in, inv, o32, obf);
  k_gates<<<NTOK_, 256, 0, stream>>>(o32, temb, Wg, bg, w2buf, gf, zbuf);
  k_reduce_gates<<<40, 256, 0, stream>>>(gf, zbuf, allg, zsum);

  // GEMM1: H' = gf .* relu(obf @ W1^T + b1)   [M=3328, N=14336, K=896]
  k_transpose<<<dim3(56, 28, 8), 256, 0, stream>>>(W1, w1t, 896, 1792, 896, (size_t)1605632);
  k_gemm8<1><<<dim3(56, 13), 512, 0, stream>>>(
      obf, w1t, 896, 896, 896, gf, b1, Hb, nullptr, 0);

  // GEMM2: ypart[z] = H' @ W2flat^T chunk  [M=3328, N=896(pad 1024), K=14336 split-P]
  k_transpose<<<dim3(32, 56, 8), 256, 0, stream>>>(W2, w2t, 1792, 896, 14336, (size_t)1792);
  k_gemm8<2><<<dim3(4, 13, P), 512, 0, stream>>>(
      Hb, w2t, 14336, 14336, 14336, nullptr, nullptr, nullptr, ypart, P);
  k_reduce_yT<<<dim3(52, 28, 2), 256, 0, stream>>>(ypart, P, gf, b2, yT);

  k_scatter<<<11501, 256, 0, stream>>>(yT, out_in, inv, dout, allg, zsum, zpart);
}

// Round 16
// 389.511 us; speedup vs baseline: 1.1521x; 1.0100x over previous
//
#include <hip/hip_runtime.h>

typedef unsigned short u16;
typedef unsigned int u32;
typedef __bf16 bf16x8 __attribute__((ext_vector_type(8)));
typedef float f32x4 __attribute__((ext_vector_type(4)));
typedef u16 u16x8 __attribute__((ext_vector_type(8)));

#define S_    896
#define TR_   1643
#define NTOK_ 3286
#define MP_   3328   // 26*128 padded token rows (per-expert row capacity)

// ---------- helpers ----------
__device__ __forceinline__ u16 f2bf(float f) {
  u32 u = __builtin_bit_cast(u32, f);
  u = (u + 0x7FFFu + ((u >> 16) & 1u)) >> 16;   // RNE
  return (u16)u;
}

__device__ __forceinline__ void gload16(const void* g, void* l) {
  __builtin_amdgcn_global_load_lds(
      (const __attribute__((address_space(1))) u32*)g,
      (__attribute__((address_space(3))) u32*)l, 16, 0, 0);
}

// ---------- init: inverse permutation + xmean zero (26 blocks: covers 6144) ----------
__global__ void k_init(const int* __restrict__ index, int* __restrict__ inv,
                       float* __restrict__ xmean) {
  int i = blockIdx.x * 256 + threadIdx.x;
  if (i < TR_) inv[index[i]] = i;
  if (i < 6144) xmean[i] = 0.f;
}

// ---------- xmean ----------
__global__ void k_reduce_x(const float* __restrict__ x, float* __restrict__ xmean) {
  int i = blockIdx.x * 256 + threadIdx.x;
  int b = i / 3072, d = i % 3072;
  int s0 = blockIdx.y * 224;
  const float* p = x + (size_t)b * S_ * 3072 + (size_t)s0 * 3072 + d;
  float s = 0.f;
  for (int t = 0; t < 224; ++t) s += p[(size_t)t * 3072];
  atomicAdd(&xmean[i], s * (1.f / (float)S_));
}

// ---------- small gating, stage 1: 24 parallel dots ----------
__global__ __launch_bounds__(256)
void k_small_dots(const float* __restrict__ xmean,
                  const float* __restrict__ Wsel, const float* __restrict__ bsel,
                  const float* __restrict__ emb,  const float* __restrict__ Wemb,
                  const float* __restrict__ bemb, float* __restrict__ glel) {
  __shared__ float red[256];
  int blk = blockIdx.x, tid = threadIdx.x;
  float s = 0.f;
  if (blk < 16) {
    int b = blk >> 3, g = blk & 7;
    for (int d = tid; d < 3072; d += 256) s += xmean[b * 3072 + d] * Wsel[d * 8 + g];
  } else {
    int g = blk - 16;
    for (int d = tid; d < 1536; d += 256) s += emb[d] * Wemb[d * 8 + g];
  }
  red[tid] = s; __syncthreads();
  for (int st = 128; st > 0; st >>= 1) { if (tid < st) red[tid] += red[tid + st]; __syncthreads(); }
  if (tid == 0) glel[blk] = red[0] + (blk < 16 ? bsel[blk & 7] : bemb[blk - 16]);
}

// ---------- small gating, stage 2: tiny tail ----------
__global__ void k_small_tail(const float* __restrict__ glel,
                             float* __restrict__ w2buf, float* __restrict__ zpart,
                             float* __restrict__ outw) {
  if (threadIdx.x != 0) return;
  const float* gl = glel;
  const float* el = glel + 16;
  float zp = 0.f;
  for (int i = 0; i < 4; ++i) {
    float e0 = el[2 * i], e1 = el[2 * i + 1];
    float m = fmaxf(e0, e1);
    float x0 = expf(e0 - m), x1 = expf(e1 - m);
    float den = x0 + x1;
    float se0 = x0 / den, se1 = x1 / den;
    zp += (e0 * e0 + e1 * e1) * 0.5f;
    float tsq = 0.f;
    for (int b = 0; b < 2; ++b) {
      float t0 = gl[b * 8 + 2 * i], t1 = gl[b * 8 + 2 * i + 1];
      tsq += t0 * t0 + t1 * t1;
      float mm = fmaxf(t0, t1);
      float y0 = expf(t0 - mm), y1 = expf(t1 - mm);
      float dd = y0 + y1;
      float w0 = (y0 / dd + se0) * 0.5f, w1 = (y1 / dd + se1) * 0.5f;
      w2buf[b * 8 + 2 * i] = w0; w2buf[b * 8 + 2 * i + 1] = w1;
      outw[b * 8 + 2 * i]  = w0; outw[b * 8 + 2 * i + 1]  = w1;
    }
    zp += tsq * 0.25f;
  }
  *zpart = zp;
}

// ---------- gather (LDS-tiled transpose; o32 only — bf16 A comes from k_gatherE) ----------
__global__ __launch_bounds__(256)
void k_gather(const float* __restrict__ out_in, const int* __restrict__ inv,
              float* __restrict__ o32) {
  __shared__ float tile[32][33];
  int b = blockIdx.z;
  int tr0 = blockIdx.x * 32, s0 = blockIdx.y * 32;
  int tx = threadIdx.x & 31, ty = threadIdx.x >> 5;
  int ntr = TR_ - tr0; if (ntr > 32) ntr = 32;
  for (int i = ty; i < 32; i += 8)
    tile[i][tx] = (tx < ntr) ? out_in[((size_t)b * S_ + s0 + i) * TR_ + tr0 + tx] : 0.f;
  __syncthreads();
  for (int r = ty; r < ntr; r += 8) {
    int t = inv[tr0 + r];
    o32[((size_t)b * TR_ + t) * S_ + s0 + tx] = tile[tx][r];
  }
}

// ---------- per-token gating (no atomics) ----------
__global__ __launch_bounds__(256)
void k_gates(const float* __restrict__ o32, const float* __restrict__ temb,
             const float* __restrict__ Wg, const float* __restrict__ bg,
             const float* __restrict__ w2buf, float* __restrict__ gf,
             float* __restrict__ zbuf) {
  int n = blockIdx.x;
  int b = n / TR_, t = n % TR_;
  int typ = (t < 228) ? 0 : (t < 519) ? 1 : (t < 1286) ? 2 : 3;
  int tid = threadIdx.x;
  const float* orow = o32 + (size_t)n * S_;
  const float* trow = temb + typ * S_;
  const float* W0 = Wg + (size_t)(2 * typ) * S_ * 8;

  float acc[16];
#pragma unroll
  for (int k = 0; k < 16; ++k) acc[k] = 0.f;
  for (int s = tid; s < S_; s += 256) {
    float ov = orow[s] + trow[s];
    const float4* wa = (const float4*)(W0 + s * 8);
    const float4* wb = (const float4*)(W0 + 7168 + s * 8);
    float4 a0 = wa[0], a1 = wa[1], b0 = wb[0], b1 = wb[1];
    acc[0]  += ov * a0.x; acc[1]  += ov * a0.y; acc[2]  += ov * a0.z; acc[3]  += ov * a0.w;
    acc[4]  += ov * a1.x; acc[5]  += ov * a1.y; acc[6]  += ov * a1.z; acc[7]  += ov * a1.w;
    acc[8]  += ov * b0.x; acc[9]  += ov * b0.y; acc[10] += ov * b0.z; acc[11] += ov * b0.w;
    acc[12] += ov * b1.x; acc[13] += ov * b1.y; acc[14] += ov * b1.z; acc[15] += ov * b1.w;
  }
#pragma unroll
  for (int k = 0; k < 16; ++k)
#pragma unroll
    for (int m = 1; m < 64; m <<= 1) acc[k] += __shfl_xor(acc[k], m, 64);

  __shared__ float wsum[4][16];
  __shared__ float lgsh[16];
  int w = tid >> 6, lane = tid & 63;
  if (lane == 0)
#pragma unroll
    for (int k = 0; k < 16; ++k) wsum[w][k] = acc[k];
  __syncthreads();
  if (tid < 16)
    lgsh[tid] = wsum[0][tid] + wsum[1][tid] + wsum[2][tid] + wsum[3][tid]
              + bg[(2 * typ + (tid >> 3)) * 8 + (tid & 7)];
  __syncthreads();

  if (tid == 0) {
    float g[8];
    for (int k = 0; k < 8; ++k) g[k] = 0.f;
    float zs[2];
    for (int j = 0; j < 2; ++j) {
      float l[8]; float ss = 0.f;
      for (int k = 0; k < 8; ++k) {
        float v = lgsh[j * 8 + k];
        v = v > 0.f ? v : 0.01f * v;
        l[k] = v; ss += v * v;
      }
      zs[j] = ss;
      int i0 = 0;
      for (int k = 1; k < 8; ++k) if (l[k] > l[i0]) i0 = k;
      int i1 = -1;
      for (int k = 0; k < 8; ++k) { if (k == i0) continue; if (i1 < 0 || l[k] > l[i1]) i1 = k; }
      int i2 = -1;
      for (int k = 0; k < 8; ++k) { if (k == i0 || k == i1) continue; if (i2 < 0 || l[k] > l[i2]) i2 = k; }
      float p1 = expf(l[i1] - l[i0]), p2 = expf(l[i2] - l[i0]);
      float den = 1.f + p1 + p2;
      float w2 = w2buf[b * 8 + 2 * typ + j];
      g[i0] += w2 / den; g[i1] += w2 * p1 / den; g[i2] += w2 * p2 / den;
    }
    float* gfp = gf + (size_t)n * 8;
    for (int k = 0; k < 8; ++k) gfp[k] = g[k];
    zbuf[n * 2 + 0] = zs[0];
    zbuf[n * 2 + 1] = zs[1];
  }
}

// ---------- segment reductions ----------
__global__ __launch_bounds__(256)
void k_reduce_gates(const float* __restrict__ gf, const float* __restrict__ zbuf,
                    float* __restrict__ allg, float* __restrict__ zsum) {
  __shared__ float red[256];
  const int s0a[4] = {0, 228, 519, 1286};
  const int cta[4] = {228, 291, 767, 357};
  int blk = blockIdx.x, tid = threadIdx.x;
  float s = 0.f;
  if (blk < 32) {
    int typ = blk >> 3, e = blk & 7;
    int s0 = s0a[typ], cnt = cta[typ];
    for (int i = tid; i < 2 * cnt; i += 256) {
      int bb = i / cnt, tt = s0 + i % cnt;
      s += gf[(size_t)(bb * TR_ + tt) * 8 + e];
    }
  } else {
    int idx = blk - 32, typ = idx >> 1, j = idx & 1;
    int s0 = s0a[typ], cnt = cta[typ];
    for (int i = tid; i < 2 * cnt; i += 256) {
      int bb = i / cnt, tt = s0 + i % cnt;
      s += zbuf[(size_t)(bb * TR_ + tt) * 2 + j];
    }
  }
  red[tid] = s; __syncthreads();
  for (int st = 128; st > 0; st >>= 1) { if (tid < st) red[tid] += red[tid + st]; __syncthreads(); }
  if (tid == 0) {
    if (blk < 32) allg[blk] = red[0];
    else          zsum[blk - 32] = red[0];
  }
}

// ---------- expert token-list build: deterministic ballot-scan (8 blocks) ----------
__global__ __launch_bounds__(256)
void k_build_lists(const float* __restrict__ gf, int* __restrict__ listE,
                   float* __restrict__ gcomp, int* __restrict__ posT,
                   int* __restrict__ cntE) {
  __shared__ int wcnt[4];
  __shared__ int sbase;
  int e = blockIdx.x;
  int tid = threadIdx.x, lane = tid & 63, wv = tid >> 6;
  if (tid == 0) sbase = 0;
  __syncthreads();
  for (int c = 0; c < 13; ++c) {
    int n = c * 256 + tid;
    float gv = (n < NTOK_) ? gf[(size_t)n * 8 + e] : 0.f;
    bool flag = (n < NTOK_) && (gv != 0.f);
    unsigned long long m = __ballot(flag);
    if (lane == 0) wcnt[wv] = __popcll(m);
    __syncthreads();
    int prefix = 0;
    for (int w = 0; w < 4; ++w) if (w < wv) prefix += wcnt[w];
    int within = __popcll(m & ((1ull << lane) - 1ull));
    if (n < NTOK_) {
      if (flag) {
        int idx = sbase + prefix + within;
        listE[e * MP_ + idx] = n;
        gcomp[e * MP_ + idx] = gv;
        posT[(size_t)n * 8 + e] = idx;
      } else {
        posT[(size_t)n * 8 + e] = -1;
      }
    }
    __syncthreads();
    if (tid == 0) sbase += wcnt[0] + wcnt[1] + wcnt[2] + wcnt[3];
    __syncthreads();
  }
  if (tid == 0) cntE[e] = sbase;
}

// ---------- gather compact per-expert bf16 A rows from o32 ----------
__global__ void k_gatherE(const float* __restrict__ o32, const int* __restrict__ listE,
                          const int* __restrict__ cntE, u16* __restrict__ obfE) {
  int idx = blockIdx.x * 256 + threadIdx.x;     // < 8*MP_*112
  int g = idx / 112, w8 = (idx % 112) * 8;
  int e = g / MP_, i = g % MP_;
  if (i >= cntE[e]) return;
  int n = listE[g];
  const float* src = o32 + (size_t)n * S_ + w8;
  float4 v0 = *(const float4*)src;
  float4 v1 = *(const float4*)(src + 4);
  u16x8 o;
  o[0] = f2bf(v0.x); o[1] = f2bf(v0.y); o[2] = f2bf(v0.z); o[3] = f2bf(v0.w);
  o[4] = f2bf(v1.x); o[5] = f2bf(v1.y); o[6] = f2bf(v1.z); o[7] = f2bf(v1.w);
  *(u16x8*)(obfE + (size_t)g * S_ + w8) = o;
}

// ---------- tiled transpose f32 -> bf16 with output-row padding ----------
__global__ __launch_bounds__(256)
void k_transpose(const float* __restrict__ W, u16* __restrict__ Wt,
                 int R, int C, int ldo, size_t eo) {
  __shared__ float tile[32][33];
  int e = blockIdx.z;
  const float* Wp = W + (size_t)e * R * C;
  u16* Wtp = Wt + (size_t)e * eo;
  int c0 = blockIdx.x * 32, r0 = blockIdx.y * 32;
  int tx = threadIdx.x & 31, ty = threadIdx.x >> 5;
  for (int i = ty; i < 32; i += 8)
    tile[i][tx] = (c0 + tx < C) ? Wp[(size_t)(r0 + i) * C + c0 + tx] : 0.f;
  __syncthreads();
  for (int i = ty; i < 32; i += 8) Wtp[(size_t)(c0 + i) * ldo + r0 + tx] = f2bf(tile[tx][i]);
}

// ---------- SPARSE 256x256x64 8-wave GEMM (frozen round-9 schedule; per-expert M) ----------
// MODE 1: per expert e: H_e = gcomp .* relu(obfE_e @ w1t_e^T + b1[e]), K=896,  N=1792 (7 tiles)
// MODE 2: per expert e: Ye_e = H_e @ w2tE_e^T (bf16 out),               K=1792, N=896p1024 (4 tiles)
// Blocks early-exit when by*256 >= cntE[e] (grid static for graph capture).
template <int MODE>
__global__ __launch_bounds__(512, 2)
void k_gemm8s(const u16* __restrict__ A, const u16* __restrict__ Bt,
              const int* __restrict__ cntE,
              const float* __restrict__ gcomp, const float* __restrict__ bias,
              u16* __restrict__ H, u16* __restrict__ Ye) {
  __shared__ __align__(16) u16 lds[2 * 32768];   // [buf][A:16384|B:16384] u16
  const int tid = threadIdx.x;
  const int lane = tid & 63;
  const int wid = tid >> 6;
  const int wr = wid >> 2, wc = wid & 3;

  const int K   = (MODE == 1) ? 896 : 1792;
  const int lda = K, ldb = K;
  const int nx  = (MODE == 1) ? 7 : 4;
  const int n8  = (MODE == 1) ? 91 : 52;        // blocks per expert (13 * nx)
  const size_t bes = (MODE == 1) ? 1605632u : 1835008u;  // B expert stride (u16)

  int f0 = (blockIdx.z * 13 + blockIdx.y) * nx + blockIdx.x;
  int f = (f0 & 7) * n8 + (f0 >> 3);            // bijective XCD swizzle (8*n8 total)
  const int ez = f / n8;
  const int r8 = f % n8;
  const int by = r8 / nx, bx = r8 % nx;

  const int cnt = cntE[ez];
  if (by * 256 >= cnt) return;

  const u16* Ag = A + ((size_t)ez * MP_ + (size_t)by * 256) * lda;
  const u16* Bg = Bt + (size_t)ez * bes + (size_t)(bx * 256) * ldb;
  const int NT = K >> 6;

#define SA(buf, g, k0)                                                          \
  { _Pragma("unroll")                                                           \
    for (int q = 0; q < 2; ++q) {                                               \
      const int br = q * 128 + (g) * 64 + wid * 8;                              \
      const int row = br + (lane >> 3);                                         \
      gload16(Ag + (size_t)row * lda + (((lane & 7) ^ (lane >> 3)) << 3) + (k0),\
              lds + (buf) * 32768 + br * 64 + lane * 8);                        \
    } }
#define SB(buf, g, k0)                                                          \
  { _Pragma("unroll")                                                           \
    for (int q = 0; q < 2; ++q) {                                               \
      const int sI = q * 8 + wid;                                               \
      const int br = (sI >> 2) * 64 + (g) * 32 + (sI & 3) * 8;                  \
      const int row = br + (lane >> 3);                                         \
      gload16(Bg + (size_t)row * ldb + (((lane & 7) ^ (lane >> 3)) << 3) + (k0),\
              lds + (buf) * 32768 + 16384 + br * 64 + lane * 8);                \
    } }
#define PSYNC(N)                                             \
  asm volatile("s_waitcnt vmcnt(" #N ")" ::: "memory");      \
  __builtin_amdgcn_s_barrier();                              \
  __builtin_amdgcn_sched_barrier(0);

  const int l15 = lane & 15, l16 = lane >> 4, l7 = lane & 7;
  const int swz0 = (l16 ^ l7) << 3;
  const int swz1 = ((4 + l16) ^ l7) << 3;
  const int rA = (wr * 128 + l15) * 64;
  const int rB = (wc * 64 + l15) * 64;

  f32x4 acc[8][4] = {};
  bf16x8 aF[4][2], b0F[2][2], b1F[2][2];

#define READ_A0  _Pragma("unroll") for (int i = 0; i < 4; ++i) {               \
    aF[i][0] = *(const bf16x8*)(lA + rA + i * 1024 + swz0);                    \
    aF[i][1] = *(const bf16x8*)(lA + rA + i * 1024 + swz1); }
#define READ_A1  _Pragma("unroll") for (int i = 0; i < 4; ++i) {               \
    aF[i][0] = *(const bf16x8*)(lA + rA + (i + 4) * 1024 + swz0);              \
    aF[i][1] = *(const bf16x8*)(lA + rA + (i + 4) * 1024 + swz1); }
#define READ_B0  _Pragma("unroll") for (int j = 0; j < 2; ++j) {               \
    b0F[j][0] = *(const bf16x8*)(lB + rB + j * 1024 + swz0);                   \
    b0F[j][1] = *(const bf16x8*)(lB + rB + j * 1024 + swz1); }
#define READ_B1  _Pragma("unroll") for (int j = 0; j < 2; ++j) {               \
    b1F[j][0] = *(const bf16x8*)(lB + rB + (j + 2) * 1024 + swz0);             \
    b1F[j][1] = *(const bf16x8*)(lB + rB + (j + 2) * 1024 + swz1); }
#define MFMA16(IB, JB, BF)                                                     \
  __builtin_amdgcn_s_setprio(1);                                               \
  _Pragma("unroll") for (int i = 0; i < 4; ++i)                                \
  _Pragma("unroll") for (int j = 0; j < 2; ++j) {                              \
    acc[i + IB][j + JB] = __builtin_amdgcn_mfma_f32_16x16x32_bf16(aF[i][0], BF[j][0], acc[i + IB][j + JB], 0, 0, 0); \
    acc[i + IB][j + JB] = __builtin_amdgcn_mfma_f32_16x16x32_bf16(aF[i][1], BF[j][1], acc[i + IB][j + JB], 0, 0, 0); \
  }                                                                            \
  __builtin_amdgcn_s_setprio(0);

  // prologue: tile 0, issue order A0,B0,B1,A1 (oldest -> newest)
  SA(0, 0, 0) SB(0, 0, 0) SB(0, 1, 0) SA(0, 1, 0)

  int cur = 0;
  for (int t = 0; t < NT - 1; ++t) {
    const u16* lA = lds + cur * 32768;
    const u16* lB = lA + 16384;
    const int nk0 = (t + 1) << 6;
    PSYNC(4)
    SA(cur ^ 1, 0, nk0) SB(cur ^ 1, 0, nk0)
    READ_A0 READ_B0
    MFMA16(0, 0, b0F)
    PSYNC(6)
    SB(cur ^ 1, 1, nk0)
    READ_B1
    MFMA16(0, 2, b1F)
    PSYNC(6)
    SA(cur ^ 1, 1, nk0)
    READ_A1
    MFMA16(4, 2, b1F)
    MFMA16(4, 0, b0F)
    cur ^= 1;
  }
  {
    const u16* lA = lds + cur * 32768;
    const u16* lB = lA + 16384;
    PSYNC(4)
    READ_A0 READ_B0
    MFMA16(0, 0, b0F)
    PSYNC(2)
    READ_B1
    MFMA16(0, 2, b1F)
    PSYNC(0)
    READ_A1
    MFMA16(4, 2, b1F)
    MFMA16(4, 0, b0F)
  }
#undef SA
#undef SB
#undef PSYNC
#undef READ_A0
#undef READ_A1
#undef READ_B0
#undef READ_B1
#undef MFMA16

  // ---- epilogue ----
  if (MODE == 1) {
#pragma unroll
    for (int j = 0; j < 4; ++j) {
      const int col = bx * 256 + wc * 64 + j * 16 + l15;   // < 1792
      const float bia = bias[ez * 1792 + col];
#pragma unroll
      for (int i = 0; i < 8; ++i)
#pragma unroll
        for (int r = 0; r < 4; ++r) {
          const int row = by * 256 + wr * 128 + i * 16 + l16 * 4 + r;
          float v = acc[i][j][r] + bia;
          v = v > 0.f ? v : 0.f;
          H[((size_t)ez * MP_ + row) * 1792 + col] = f2bf(v * gcomp[ez * MP_ + row]);
        }
    }
  } else {
#pragma unroll
    for (int j = 0; j < 4; ++j) {
      const int col = bx * 256 + wc * 64 + j * 16 + l15;
      if (col < 896) {
#pragma unroll
        for (int i = 0; i < 8; ++i)
#pragma unroll
          for (int r = 0; r < 4; ++r) {
            const int row = by * 256 + wr * 128 + i * 16 + l16 * 4 + r;
            Ye[((size_t)ez * MP_ + row) * 896 + col] = f2bf(acc[i][j][r]);
          }
      }
    }
  }
}

// ---------- combine: yT[b,s,t] = sum_e Ye[e][pos[n,e]][s] + sum_e gf[n,e]*b2[e,s] ----------
__global__ __launch_bounds__(256)
void k_combine(const u16* __restrict__ YeE, const int* __restrict__ posT,
               const float* __restrict__ gf, const float* __restrict__ b2,
               float* __restrict__ yT) {
  __shared__ float tile[32][33];
  int b = blockIdx.z;
  int t0 = blockIdx.x * 32, s0 = blockIdx.y * 32;
  int tx = threadIdx.x & 31, ty = threadIdx.x >> 5;
  int ntv = TR_ - t0; if (ntv > 32) ntv = 32;
  for (int r = ty; r < 32; r += 8) {
    float acc = 0.f;
    if (r < ntv) {
      size_t n = (size_t)b * TR_ + t0 + r;
      const int* pp = posT + n * 8;
      const float* g = gf + n * 8;
      int s = s0 + tx;
#pragma unroll
      for (int e = 0; e < 8; ++e) {
        int p = pp[e];
        if (p >= 0) {
          u32 hv = YeE[((size_t)e * MP_ + p) * 896 + s];
          acc += __builtin_bit_cast(float, hv << 16);
        }
        acc += g[e] * b2[e * 896 + s];
      }
    }
    tile[r][tx] = acc;
  }
  __syncthreads();
  for (int i = ty; i < 32; i += 8)
    if (tx < ntv)
      yT[((size_t)b * S_ + s0 + i) * TR_ + t0 + tx] = tile[tx][i];
}

// ---------- scatter + fused finalize ----------
__global__ void k_scatter(const float* __restrict__ yT, const float* __restrict__ out_in,
                          const int* __restrict__ inv, float* __restrict__ dout,
                          const float* __restrict__ allg, const float* __restrict__ zsum,
                          const float* __restrict__ zpart) {
  int i = blockIdx.x * 256 + threadIdx.x;   // < B*S*TR = 2944256 exactly
  int tr = i % TR_;
  dout[i] = out_in[i] + yT[(size_t)(i - tr) + inv[tr]];
  if (blockIdx.x == 0) {
    int tid = threadIdx.x;
    if (tid < 32) dout[2944256 + tid] = allg[tid];
    else if (tid == 32) {
      float z = *zpart;
      const int Ts[4] = {228, 291, 767, 357};
      for (int q = 0; q < 4; ++q)
        for (int j = 0; j < 2; ++j)
          z += zsum[q * 2 + j] / (float)(2 * Ts[q] * 8);
      dout[2944288] = z;
      dout[2944289] = 0.f;
    }
  }
}

extern "C" void kernel_launch(void* const* d_in, const int* in_sizes, int n_in,
                              void* d_out, int out_size, void* d_ws, size_t ws_size,
                              hipStream_t stream) {
  const float* x         = (const float*)d_in[0];
  const float* out_in    = (const float*)d_in[1];
  const float* embedding = (const float*)d_in[2];
  const int*   index     = (const int*)d_in[3];
  const float* Wsel      = (const float*)d_in[4];
  const float* bsel      = (const float*)d_in[5];
  const float* Wemb      = (const float*)d_in[6];
  const float* bemb      = (const float*)d_in[7];
  const float* Wg        = (const float*)d_in[8];
  const float* bg        = (const float*)d_in[9];
  const float* temb      = (const float*)d_in[10];
  const float* W1        = (const float*)d_in[11];
  const float* b1        = (const float*)d_in[12];
  const float* W2        = (const float*)d_in[13];
  const float* b2        = (const float*)d_in[14];
  float* dout = (float*)d_out;

  char* ws = (char*)d_ws;
  float* allg  = (float*)(ws + 0);           // 32 f
  float* zsum  = (float*)(ws + 128);         // 8 f
  float* zpart = (float*)(ws + 160);         // 1 f
  float* w2buf = (float*)(ws + 192);         // 16 f
  int*   inv   = (int*)(ws + 256);           // 1643 i -> 6828
  float* glel  = (float*)(ws + 6912);        // 24 f
  int*   cntE  = (int*)(ws + 7040);          // 8 i
  float* xmean = (float*)(ws + 8192);        // 6144 f -> 32768
  float* gf    = (float*)(ws + 32768);       // MP*8 f -> 139264
  float* o32   = (float*)(ws + 139264);      // MP*896 f -> 12066816 (reused as yT)
  float* yT    = o32;
  float* zbuf  = (float*)(ws + 139264 + (size_t)NTOK_ * S_ * 4);
  int*   posT  = (int*)(ws + 12066816);      // NTOK*8 i -> 12171968
  int*   listE = (int*)(ws + 12171968);      // 8*MP i  -> 12278464
  float* gcomp = (float*)(ws + 12278464);    // 8*MP f  -> 12384960
  u16*   w1t   = (u16*)(ws + 12386304);      // 8*1792*896 bf16 -> 38076416
  u16*   w2tE  = (u16*)(ws + 38076416);      // 8*1024*1792 bf16 -> 67436544
  u16*   obfE  = (u16*)(ws + 67436544);      // 8*MP*896 bf16 -> 115146752 (dead after GEMM1)
  u16*   YeE   = obfE;                       // GEMM2 output overlays obfE
  u16*   HbE   = (u16*)(ws + 115146752);     // 8*MP*1792 bf16 -> 210567168
  // high-water 210.6 MB < 277.5 MB (P=8 dense tier, proven to fit in rounds 8-15)

  k_init<<<26, 256, 0, stream>>>(index, inv, xmean);
  k_reduce_x<<<dim3(24, 4), 256, 0, stream>>>(x, xmean);
  k_small_dots<<<24, 256, 0, stream>>>(xmean, Wsel, bsel, embedding, Wemb, bemb, glel);
  k_small_tail<<<1, 64, 0, stream>>>(glel, w2buf, zpart, dout + 2944290);
  k_gather<<<dim3(52, 28, 2), 256, 0, stream>>>(out_in, inv, o32);
  k_gates<<<NTOK_, 256, 0, stream>>>(o32, temb, Wg, bg, w2buf, gf, zbuf);
  k_reduce_gates<<<40, 256, 0, stream>>>(gf, zbuf, allg, zsum);

  // expert compaction (round-15: ~39% of gf entries are exactly zero)
  k_build_lists<<<8, 256, 0, stream>>>(gf, listE, gcomp, posT, cntE);
  k_gatherE<<<11648, 256, 0, stream>>>(o32, listE, cntE, obfE);

  // GEMM1-sparse: per-expert H_e = gcomp .* relu(A_e @ W1_e^T + b1_e)
  k_transpose<<<dim3(56, 28, 8), 256, 0, stream>>>(W1, w1t, 896, 1792, 896, (size_t)1605632);
  k_gemm8s<1><<<dim3(7, 13, 8), 512, 0, stream>>>(obfE, w1t, cntE, gcomp, b1, HbE, nullptr);

  // GEMM2-sparse: per-expert Ye_e = H_e @ W2_e^T (bf16), K=1792
  k_transpose<<<dim3(32, 56, 8), 256, 0, stream>>>(W2, w2tE, 1792, 896, 1792, (size_t)1835008);
  k_gemm8s<2><<<dim3(4, 13, 8), 512, 0, stream>>>(HbE, w2tE, cntE, nullptr, nullptr, nullptr, YeE);

  k_combine<<<dim3(52, 28, 2), 256, 0, stream>>>(YeE, posT, gf, b2, yT);
  k_scatter<<<11501, 256, 0, stream>>>(yT, out_in, inv, dout, allg, zsum, zpart);
}